// Round 1
// baseline (94.047 us; speedup 1.0000x reference)
//
#include <hip/hip_runtime.h>

#define Bn 128
#define Qn 32
#define Dn 512
#define En 300
#define Kn 21
#define CHUNK 128      // docs per block
#define NCHUNK 4
#define GRP 32         // docs per group
#define LDQ 308        // padded row stride in floats (308 % 8 == 4 -> conflict-free 8-row b128 reads)
#define NF4 75         // valid float4s per row (300/4)
#define LDF4 77        // float4 slots per padded row (308/4)
#define NTHR 512

__device__ __forceinline__ float dot4(float4 a, float4 b) {
    return a.x * b.x + a.y * b.y + a.z * b.z + a.w * b.w;
}
__device__ __forceinline__ float4 scale4(float4 v, float s) {
    return make_float4(v.x * s, v.y * s, v.z * s, v.w * s);
}

// Stage one table row (normalized) into an LDS row. Wave-cooperative.
__device__ __forceinline__ void stage_row(const float* __restrict__ table, int row,
                                          float* __restrict__ dst_row, int lane)
{
    const float4* src = (const float4*)(table + (size_t)row * En);
    float4 v0 = src[lane];                       // lane 0..63 < 75 always valid
    float4 v1 = make_float4(0.f, 0.f, 0.f, 0.f);
    const int f1 = lane + 64;
    if (f1 < NF4) v1 = src[f1];
    float ss = dot4(v0, v0) + dot4(v1, v1);
    #pragma unroll
    for (int o = 1; o < 64; o <<= 1) ss += __shfl_xor(ss, o);
    const float inv = 1.0f / fmaxf(sqrtf(ss), 1e-12f);
    float4* dst = (float4*)dst_row;
    dst[lane] = scale4(v0, inv);
    if (f1 < LDF4) {
        dst[f1] = (f1 < NF4) ? scale4(v1, inv) : make_float4(0.f, 0.f, 0.f, 0.f);
    }
}

__global__ __launch_bounds__(NTHR, 1)
void knrm_main(const int* __restrict__ qidx, const int* __restrict__ didx,
               const int* __restrict__ dlen_arr, const float* __restrict__ table,
               float* __restrict__ partial)
{
    // 112.6 KB LDS total -> 1 block/CU on gfx950 (160 KB limit)
    __shared__ float q_lds[Qn * LDQ];                 // 39424 B
    __shared__ float d_lds[GRP * LDQ];                // 39424 B
    __shared__ float simb[8 * Qn * (GRP + 1)];        // 33792 B (padded to 33 cols)

    const int t = threadIdx.x;
    const int lane = t & 63;
    const int w = t >> 6;                 // wave 0..7
    const int b = blockIdx.x >> 2;        // batch
    const int chunk = blockIdx.x & 3;     // doc chunk of 128
    const int dlen = dlen_arr[b];

    // ---- stage + normalize 32 query rows (4 per wave)
    #pragma unroll
    for (int qi = 0; qi < 4; ++qi) {
        const int q = w * 4 + qi;
        stage_row(table, qidx[b * Qn + q], q_lds + q * LDQ, lane);
    }

    // sim-tile ownership: thread handles q rows {qg+8i}, d rows {dg+8j}
    const int qg = (t >> 3) & 7;
    const int dg = t & 7;
    const int fbeg = w * 10;
    const int fend = (fbeg + 10 < LDF4) ? (fbeg + 10) : LDF4;

    // pooling ownership: 16 threads per q
    const int pq = t >> 4;
    const int pj = t & 15;

    float acck[Kn];
    #pragma unroll
    for (int k = 0; k < Kn; ++k) acck[k] = 0.f;

    const int nvalid = dlen - chunk * CHUNK;
    int ngrp = (nvalid + GRP - 1) / GRP;
    if (ngrp < 0) ngrp = 0;
    if (ngrp > 4) ngrp = 4;

    for (int g = 0; g < ngrp; ++g) {
        // ---- stage + normalize up to 32 doc rows (4 per wave), skip masked docs
        #pragma unroll
        for (int di = 0; di < 4; ++di) {
            const int dloc = w * 4 + di;
            const int dglob = chunk * CHUNK + g * GRP + dloc;
            if (dglob < dlen) {
                stage_row(table, didx[b * Dn + dglob], d_lds + dloc * LDQ, lane);
            }
        }
        __syncthreads();

        // ---- partial sims over this wave's E-slice: 4q x 4d register tile
        float acc[4][4];
        #pragma unroll
        for (int i = 0; i < 4; ++i)
            #pragma unroll
            for (int j = 0; j < 4; ++j) acc[i][j] = 0.f;

        for (int f = fbeg; f < fend; ++f) {
            float4 qv[4], dv[4];
            #pragma unroll
            for (int i = 0; i < 4; ++i)
                qv[i] = ((const float4*)(q_lds + (qg + 8 * i) * LDQ))[f];
            #pragma unroll
            for (int j = 0; j < 4; ++j)
                dv[j] = ((const float4*)(d_lds + (dg + 8 * j) * LDQ))[f];
            #pragma unroll
            for (int i = 0; i < 4; ++i)
                #pragma unroll
                for (int j = 0; j < 4; ++j)
                    acc[i][j] += dot4(qv[i], dv[j]);
        }

        #pragma unroll
        for (int i = 0; i < 4; ++i)
            #pragma unroll
            for (int j = 0; j < 4; ++j)
                simb[(w * Qn + (qg + 8 * i)) * (GRP + 1) + (dg + 8 * j)] = acc[i][j];
        __syncthreads();

        // ---- kernel pooling: thread (pq, pj) handles docs pj and pj+16
        #pragma unroll
        for (int dd = 0; dd < 2; ++dd) {
            const int dloc = pj + 16 * dd;
            const int dglob = chunk * CHUNK + g * GRP + dloc;
            if (dglob < dlen) {
                float s = 0.f;
                #pragma unroll
                for (int w2 = 0; w2 < 8; ++w2)
                    s += simb[(w2 * Qn + pq) * (GRP + 1) + dloc];
                #pragma unroll
                for (int k = 0; k < Kn; ++k) {
                    const float mu = (k == 0) ? 1.0f : (0.95f - 0.1f * (float)(k - 1));
                    const float cf = (k == 0) ? -500000.0f : -50.0f;  // -1/(2*sigma^2)
                    const float df = s - mu;
                    acck[k] += __expf(cf * df * df);
                }
            }
        }
        __syncthreads();
    }

    // ---- reduce pooling accumulators over the 16 threads of each q
    #pragma unroll
    for (int o = 1; o < 16; o <<= 1) {
        #pragma unroll
        for (int k = 0; k < Kn; ++k) acck[k] += __shfl_xor(acck[k], o);
    }

    float* pp = partial + (((size_t)b * NCHUNK + chunk) * Qn + pq) * Kn;
    pp[pj] = acck[pj];                    // pj 0..15 < 21 always
    const int k2 = pj + 16;
    if (k2 < Kn) pp[k2] = acck[k2];
}

__global__ void knrm_reduce(const int* __restrict__ qlen_arr,
                            const float* __restrict__ partial,
                            const float* __restrict__ dense_w,
                            const float* __restrict__ dense_b,
                            float* __restrict__ out)
{
    const int b = blockIdx.x;
    const int k = threadIdx.x;
    __shared__ float lp[Kn];
    const int qlen = qlen_arr[b];
    if (k < Kn) {
        float acc = 0.f;
        for (int q = 0; q < Qn; ++q) {
            float s = 0.f;
            #pragma unroll
            for (int c = 0; c < NCHUNK; ++c)
                s += partial[(((size_t)b * NCHUNK + c) * Qn + q) * Kn + k];
            if (q < qlen) acc += 0.01f * logf(fmaxf(s, 1e-10f));
        }
        out[Bn + (size_t)b * Kn + k] = acc;   // log_pooling_sum (B,K)
        lp[k] = acc;
    }
    __syncthreads();
    if (k == 0) {
        float sc = dense_b[0];
        #pragma unroll
        for (int kk = 0; kk < Kn; ++kk) sc += lp[kk] * dense_w[kk];
        out[b] = sc;                          // score (B,)
    }
}

extern "C" void kernel_launch(void* const* d_in, const int* in_sizes, int n_in,
                              void* d_out, int out_size, void* d_ws, size_t ws_size,
                              hipStream_t stream)
{
    const int*   qidx  = (const int*)d_in[0];
    const int*   didx  = (const int*)d_in[1];
    const int*   qlen  = (const int*)d_in[2];
    const int*   dlen  = (const int*)d_in[3];
    const float* table = (const float*)d_in[4];
    const float* dw    = (const float*)d_in[5];
    const float* db    = (const float*)d_in[6];
    float* out = (float*)d_out;
    float* partial = (float*)d_ws;   // B*NCHUNK*Qn*Kn floats = 1.31 MB, fully overwritten

    knrm_main<<<dim3(Bn * NCHUNK), dim3(NTHR), 0, stream>>>(qidx, didx, dlen, table, partial);
    knrm_reduce<<<dim3(Bn), dim3(64), 0, stream>>>(qlen, partial, dw, db, out);
}

// Round 2
// 60.560 us; speedup vs baseline: 1.5530x; 1.5530x over previous
//
#include <hip/hip_runtime.h>

#define Bn 128
#define Qn 32
#define Dn 512
#define En 300
#define Kn 21
#define DC 64            // docs per block
#define NCHUNK 8         // 512/DC
#define NROWS 96         // 32 q rows + 64 d rows
#define KT_PASS 5        // k-tiles (of 32) per staging pass; 2 passes cover 320 (>=300, zero-padded)
#define LDE 40           // bf16 row stride inside one k-tile (40*2B = 80B, 16B-aligned, 2-way banks max)
#define SIMLD 68         // simbuf stride in floats (68 % 32 == 4 -> <=2-way on write/read)
#define NTHR 256

typedef __attribute__((ext_vector_type(8))) short bf16x8;
typedef __attribute__((ext_vector_type(4))) float f32x4;
typedef __attribute__((ext_vector_type(4))) short short4v;

// LDS layout (bytes)
#define EMB_OFF 0                        // short [KT_PASS][NROWS][LDE] = 5*96*40*2 = 38400
#define SIM_OFF 38400                    // float [Qn][SIMLD]           = 8704
#define NRM_OFF (38400 + 8704)           // float [96]: invq[32], invd[64]
#define POOL_OFF 0                       // float [Qn][8][Kn] = 21504  (aliases EMB, used after)
#define SMEM_BYTES (38400 + 8704 + 384)  // 47488 B -> 3 blocks/CU

__device__ __forceinline__ unsigned short f2bf(float x) {
    // round-to-nearest-even fp32 -> bf16 (finite inputs only)
    unsigned u = __float_as_uint(x);
    unsigned r = (u + 0x7FFFu + ((u >> 16) & 1u)) >> 16;
    return (unsigned short)r;
}

__global__ __launch_bounds__(NTHR, 3)
void knrm_main(const int* __restrict__ qidx, const int* __restrict__ didx,
               const int* __restrict__ dlen_arr, const float* __restrict__ table,
               float* __restrict__ partial)
{
    __shared__ __align__(16) char smem[SMEM_BYTES];
    short* emb    = (short*)(smem + EMB_OFF);
    float* simbuf = (float*)(smem + SIM_OFF);
    float* nrm    = (float*)(smem + NRM_OFF);
    float* pool   = (float*)(smem + POOL_OFF);

    const int t = threadIdx.x;
    const int b = blockIdx.x >> 3;
    const int chunk = blockIdx.x & 7;
    const int dlen = dlen_arr[b];

    float* pbase = partial + (((size_t)b * NCHUNK + chunk) * Qn) * Kn;  // 672 floats

    const int nvalid = dlen - chunk * DC;
    if (nvalid <= 0) {  // whole chunk masked: emit zero partials (ws is poisoned, must overwrite)
        for (int i = t; i < Qn * Kn; i += NTHR) pbase[i] = 0.f;
        return;
    }

    const int lane = t & 63;
    const int w = t >> 6;            // wave 0..3
    const int qt = w & 1;            // q-tile (16 rows)
    const int dt0 = (w >> 1) * 2;    // first of two d-tiles
    const int frow = lane & 15;      // fragment row/col
    const int koct = lane >> 4;      // k-octet 0..3

    f32x4 accS0 = {0.f,0.f,0.f,0.f}, accS1 = {0.f,0.f,0.f,0.f};
    f32x4 accG  = {0.f,0.f,0.f,0.f};   // d-gram (wave w -> d-tile w)
    f32x4 accQ  = {0.f,0.f,0.f,0.f};   // q-gram (waves 0,1 -> q-tiles 0,1)

    for (int pass = 0; pass < 2; ++pass) {
        // ---- stage 96 rows x 160 e (raw bf16, zero-padded, no normalization)
        for (int u = t; u < NROWS * 40; u += NTHR) {
            const int r  = u / 40;
            const int fl = u - r * 40;           // float4 slot within pass
            const int k  = pass * 160 + fl * 4;
            short4v v = {0, 0, 0, 0};
            bool valid; int tok;
            if (r < Qn) { valid = (k < En); tok = qidx[b * Qn + r]; }
            else {
                const int dglob = chunk * DC + (r - Qn);
                valid = (k < En) && (dglob < dlen);
                tok = didx[b * Dn + dglob];
            }
            if (valid) {
                const float4 f = *(const float4*)(table + (size_t)tok * En + k);
                v.x = (short)f2bf(f.x); v.y = (short)f2bf(f.y);
                v.z = (short)f2bf(f.z); v.w = (short)f2bf(f.w);
            }
            *(short4v*)&emb[((fl >> 3) * NROWS + r) * LDE + (fl & 7) * 4] = v;
        }
        __syncthreads();

        // ---- 5 k-tiles of MFMA: 2 sim tiles + 1 d-gram (+1 q-gram on waves 0,1)
        for (int kt = 0; kt < KT_PASS; ++kt) {
            const short* base = &emb[kt * NROWS * LDE];
            bf16x8 a  = *(const bf16x8*)&base[(qt * 16 + frow) * LDE + koct * 8];
            bf16x8 b0 = *(const bf16x8*)&base[(Qn + dt0 * 16 + frow) * LDE + koct * 8];
            bf16x8 b1 = *(const bf16x8*)&base[(Qn + dt0 * 16 + 16 + frow) * LDE + koct * 8];
            accS0 = __builtin_amdgcn_mfma_f32_16x16x32_bf16(a, b0, accS0, 0, 0, 0);
            accS1 = __builtin_amdgcn_mfma_f32_16x16x32_bf16(a, b1, accS1, 0, 0, 0);
            bf16x8 gb = (w & 1) ? b1 : b0;       // wave w grams d-tile w
            accG = __builtin_amdgcn_mfma_f32_16x16x32_bf16(gb, gb, accG, 0, 0, 0);
            if (w < 2) accQ = __builtin_amdgcn_mfma_f32_16x16x32_bf16(a, a, accQ, 0, 0, 0);
        }
        __syncthreads();
    }

    // ---- extract gram diagonals -> inverse norms in LDS
    // C layout: col = lane&15, row = (lane>>4)*4 + reg. Diag r held where koct == frow>>2, reg = frow&3.
    if (koct == (frow >> 2)) {
        const int rm = frow & 3;
        float gd = (rm == 0) ? accG[0] : (rm == 1) ? accG[1] : (rm == 2) ? accG[2] : accG[3];
        nrm[Qn + w * 16 + frow] = 1.0f / fmaxf(sqrtf(gd), 1e-12f);
        if (w < 2) {
            float qd = (rm == 0) ? accQ[0] : (rm == 1) ? accQ[1] : (rm == 2) ? accQ[2] : accQ[3];
            nrm[w * 16 + frow] = 1.0f / fmaxf(sqrtf(qd), 1e-12f);
        }
    }
    __syncthreads();

    // ---- scale by invq*invd, write sim tile to LDS
    const float id0 = nrm[Qn + dt0 * 16 + frow];
    const float id1 = nrm[Qn + dt0 * 16 + 16 + frow];
    #pragma unroll
    for (int reg = 0; reg < 4; ++reg) {
        const int q = qt * 16 + koct * 4 + reg;
        const float iq = nrm[q];
        simbuf[q * SIMLD + dt0 * 16 + frow]      = accS0[reg] * iq * id0;
        simbuf[q * SIMLD + dt0 * 16 + 16 + frow] = accS1[reg] * iq * id1;
    }
    __syncthreads();

    // ---- Gaussian kernel pooling: thread (q, dl) accumulates 8 docs
    const int pq = t >> 3;
    const int pdl = t & 7;
    float acck[Kn];
    #pragma unroll
    for (int k = 0; k < Kn; ++k) acck[k] = 0.f;
    #pragma unroll
    for (int j = 0; j < 8; ++j) {
        const int d = pdl + 8 * j;
        if (chunk * DC + d < dlen) {
            const float s = simbuf[pq * SIMLD + d];
            #pragma unroll
            for (int k = 0; k < Kn; ++k) {
                const float mu = (k == 0) ? 1.0f : (0.95f - 0.1f * (float)(k - 1));
                const float cf = (k == 0) ? -500000.0f : -50.0f;  // -1/(2*sigma^2)
                const float df = s - mu;
                acck[k] += __expf(cf * df * df);
            }
        }
    }
    // pool buffer aliases emb (emb dead since last MFMA + 2 barriers)
    #pragma unroll
    for (int k = 0; k < Kn; ++k) pool[(pq * 8 + pdl) * Kn + k] = acck[k];
    __syncthreads();

    // ---- reduce the 8 doc-lanes, write per-chunk partial (coalesced)
    for (int i = t; i < Qn * Kn; i += NTHR) {
        const int q = i / Kn;
        const int k = i - q * Kn;
        float s = 0.f;
        #pragma unroll
        for (int dl = 0; dl < 8; ++dl) s += pool[(q * 8 + dl) * Kn + k];
        pbase[i] = s;
    }
}

__global__ __launch_bounds__(704)
void knrm_reduce(const int* __restrict__ qlen_arr, const float* __restrict__ partial,
                 const float* __restrict__ dense_w, const float* __restrict__ dense_b,
                 float* __restrict__ out)
{
    __shared__ float sq[Qn * Kn];
    __shared__ float lk[Kn];
    const int b = blockIdx.x;
    const int t = threadIdx.x;
    const int qlen = qlen_arr[b];
    if (t < Qn * Kn) {
        const int q = t / Kn, k = t - q * Kn;
        float s = 0.f;
        #pragma unroll
        for (int c = 0; c < NCHUNK; ++c)
            s += partial[(((size_t)b * NCHUNK + c) * Qn + q) * Kn + k];
        sq[t] = (q < qlen) ? 0.01f * logf(fmaxf(s, 1e-10f)) : 0.f;
    }
    __syncthreads();
    if (t < Kn) {
        float l = 0.f;
        #pragma unroll
        for (int q = 0; q < Qn; ++q) l += sq[q * Kn + t];
        out[Bn + (size_t)b * Kn + t] = l;   // log_pooling_sum (B,K)
        lk[t] = l;
    }
    __syncthreads();
    if (t == 0) {
        float sc = dense_b[0];
        #pragma unroll
        for (int k = 0; k < Kn; ++k) sc += lk[k] * dense_w[k];
        out[b] = sc;                        // score (B,)
    }
}

extern "C" void kernel_launch(void* const* d_in, const int* in_sizes, int n_in,
                              void* d_out, int out_size, void* d_ws, size_t ws_size,
                              hipStream_t stream)
{
    const int*   qidx  = (const int*)d_in[0];
    const int*   didx  = (const int*)d_in[1];
    const int*   qlen  = (const int*)d_in[2];
    const int*   dlen  = (const int*)d_in[3];
    const float* table = (const float*)d_in[4];
    const float* dw    = (const float*)d_in[5];
    const float* db    = (const float*)d_in[6];
    float* out = (float*)d_out;
    float* partial = (float*)d_ws;   // B*NCHUNK*Qn*Kn floats = 2.75 MB, fully overwritten each launch

    knrm_main<<<dim3(Bn * NCHUNK), dim3(NTHR), 0, stream>>>(qidx, didx, dlen, table, partial);
    knrm_reduce<<<dim3(Bn), dim3(704), 0, stream>>>(qlen, partial, dw, db, out);
}

// Round 3
// 36.316 us; speedup vs baseline: 2.5897x; 1.6676x over previous
//
#include <hip/hip_runtime.h>

#define Bn 128
#define Qn 32
#define Dn 512
#define En 300
#define Kn 21
#define DC 64            // docs per block
#define NCHUNK 8         // 512/DC
#define NROWS 96         // 32 q + 64 d rows
#define LDE 40           // bf16 row stride within one k-tile
#define TILE_STRIDE (NROWS * LDE + 8)   // +16B skew per k-tile (bank spread)
#define SIMLD 68         // sim row stride (floats)
#define NTHR 512
#define NLD (NROWS * 40) // 3840 float4 slots per pass

typedef __attribute__((ext_vector_type(8))) short bf16x8;
typedef __attribute__((ext_vector_type(4))) float f32x4;
typedef __attribute__((ext_vector_type(4))) short short4v;

// LDS: emb = short[5][TILE_STRIDE] = 38480 B; idx = int[96] at end.
// After last MFMA (emb dead), aliased into emb bytes:
//   simbuf float[32][68] @ [0, 8704)
//   nrm    float[96]     @ [8704, 9088)
//   poolbuf float[672]   @ [9088, 11776)
#define EMB_BYTES (5 * TILE_STRIDE * 2)
#define SMEM_BYTES (EMB_BYTES + NROWS * 4)   // 38864 B

__device__ __forceinline__ unsigned short f2bf(float x) {
    unsigned u = __float_as_uint(x);
    return (unsigned short)((u + 0x7FFFu + ((u >> 16) & 1u)) >> 16);
}

__global__ __launch_bounds__(NTHR, 4)
void knrm_main(const int* __restrict__ qidx, const int* __restrict__ didx,
               const int* __restrict__ dlen_arr, const float* __restrict__ table,
               float* __restrict__ partial)
{
    const int t = threadIdx.x;
    const int b = blockIdx.x >> 3;
    const int chunk = blockIdx.x & 7;
    const int dlen = dlen_arr[b];
    float* pbase = partial + ((size_t)(b * NCHUNK + chunk) * Qn) * Kn;

    const int nvalid = dlen - chunk * DC;
    if (nvalid <= 0) {                 // whole chunk masked: zero partials (ws poisoned)
        for (int i = t; i < Qn * Kn; i += NTHR) pbase[i] = 0.f;
        return;
    }

    __shared__ __align__(16) char smem[SMEM_BYTES];
    short* emb    = (short*)smem;
    float* simbuf = (float*)smem;
    float* nrm    = (float*)(smem + 8704);
    float* poolbf = (float*)(smem + 9088);
    int*   idxb   = (int*)(smem + EMB_BYTES);

    // ---- stage token ids once
    if (t < NROWS) {
        int tok = 0;
        if (t < Qn) tok = qidx[b * Qn + t];
        else { const int dg = chunk * DC + (t - Qn); if (dg < dlen) tok = didx[b * Dn + dg]; }
        idxb[t] = tok;
    }
    __syncthreads();

    const int lane = t & 63;
    const int w = t >> 6;            // wave 0..7
    const int qt = w & 1;            // q-tile
    const int dt = w >> 1;           // d-tile
    const int frow = lane & 15;
    const int koct = lane >> 4;

    f32x4 accS = {0.f,0.f,0.f,0.f};
    f32x4 accG = {0.f,0.f,0.f,0.f};  // waves 0,2,4,6: d-gram of tile dt
    f32x4 accQ = {0.f,0.f,0.f,0.f};  // waves 0,1: q-gram of tile qt

    float4 ld[8];

    // ---- issue: 8 independent gathers into regs (no per-iter dependence)
    #define ISSUE(pass)                                                          \
        _Pragma("unroll")                                                        \
        for (int i = 0; i < 8; ++i) {                                            \
            const int u = t + i * NTHR;                                          \
            float4 v = {0.f,0.f,0.f,0.f};                                        \
            if (u < NLD) {                                                       \
                const int r = u / 40, fl = u - r * 40;                           \
                const int k = (pass) * 160 + fl * 4;                             \
                bool valid = (k < En);                                           \
                if (r >= Qn) valid = valid && (chunk * DC + (r - Qn) < dlen);    \
                if (valid) v = *(const float4*)(table + (size_t)idxb[r] * En + k); \
            }                                                                    \
            ld[i] = v;                                                           \
        }

    // ---- commit: convert + LDS write (single waitcnt drain at first use)
    #define COMMIT()                                                             \
        _Pragma("unroll")                                                        \
        for (int i = 0; i < 8; ++i) {                                            \
            const int u = t + i * NTHR;                                          \
            if (u < NLD) {                                                       \
                const int r = u / 40, fl = u - r * 40;                           \
                short4v s;                                                       \
                s.x = (short)f2bf(ld[i].x); s.y = (short)f2bf(ld[i].y);          \
                s.z = (short)f2bf(ld[i].z); s.w = (short)f2bf(ld[i].w);          \
                *(short4v*)&emb[(fl >> 3) * TILE_STRIDE + r * LDE + (fl & 7) * 4] = s; \
            }                                                                    \
        }

    #define MFMA_PASS()                                                          \
        _Pragma("unroll")                                                        \
        for (int kt = 0; kt < 5; ++kt) {                                         \
            const short* base = &emb[kt * TILE_STRIDE];                          \
            bf16x8 a  = *(const bf16x8*)&base[(qt * 16 + frow) * LDE + koct * 8];\
            bf16x8 bb = *(const bf16x8*)&base[(Qn + dt * 16 + frow) * LDE + koct * 8]; \
            accS = __builtin_amdgcn_mfma_f32_16x16x32_bf16(a, bb, accS, 0, 0, 0);\
            if ((w & 1) == 0) accG = __builtin_amdgcn_mfma_f32_16x16x32_bf16(bb, bb, accG, 0, 0, 0); \
            if (w < 2)        accQ = __builtin_amdgcn_mfma_f32_16x16x32_bf16(a, a, accQ, 0, 0, 0);   \
        }

    ISSUE(0)
    COMMIT()
    __syncthreads();
    ISSUE(1)            // pass-1 gather latency hides under pass-0 MFMA
    MFMA_PASS()
    __syncthreads();    // all waves done reading pass-0 emb
    COMMIT()
    __syncthreads();
    MFMA_PASS()
    __syncthreads();    // emb dead -> safe to alias sim/nrm/pool

    // ---- gram diagonals -> inverse norms (C layout: col=lane&15, row=koct*4+reg)
    if (koct == (frow >> 2)) {
        const int rm = frow & 3;
        if ((w & 1) == 0) {
            const float g = (rm == 0) ? accG[0] : (rm == 1) ? accG[1] : (rm == 2) ? accG[2] : accG[3];
            nrm[Qn + dt * 16 + frow] = 1.0f / fmaxf(sqrtf(g), 1e-12f);
        }
        if (w < 2) {
            const float g = (rm == 0) ? accQ[0] : (rm == 1) ? accQ[1] : (rm == 2) ? accQ[2] : accQ[3];
            nrm[qt * 16 + frow] = 1.0f / fmaxf(sqrtf(g), 1e-12f);
        }
    }
    __syncthreads();

    // ---- scale sims, write tile
    const float id = nrm[Qn + dt * 16 + frow];
    #pragma unroll
    for (int reg = 0; reg < 4; ++reg) {
        const int q = qt * 16 + koct * 4 + reg;
        simbuf[q * SIMLD + dt * 16 + frow] = accS[reg] * nrm[q] * id;
    }
    __syncthreads();

    // ---- Gaussian pooling: 16 lanes per q, 4 docs each
    const int pq = t >> 4;
    const int pdl = t & 15;
    float acck[Kn];
    #pragma unroll
    for (int k = 0; k < Kn; ++k) acck[k] = 0.f;
    #pragma unroll
    for (int j = 0; j < 4; ++j) {
        const int d = pdl + 16 * j;
        if (chunk * DC + d < dlen) {
            const float s = simbuf[pq * SIMLD + d];
            #pragma unroll
            for (int k = 0; k < Kn; ++k) {
                const float mu = (k == 0) ? 1.0f : (0.95f - 0.1f * (float)(k - 1));
                const float cf = (k == 0) ? -500000.0f : -50.0f;  // -1/(2*sigma^2)
                const float df = s - mu;
                acck[k] += __expf(cf * df * df);
            }
        }
    }
    #pragma unroll
    for (int o = 1; o < 16; o <<= 1) {
        #pragma unroll
        for (int k = 0; k < Kn; ++k) acck[k] += __shfl_xor(acck[k], o);
    }
    if (pdl == 0) {                    // static-index writes only (rule #20)
        #pragma unroll
        for (int k = 0; k < Kn; ++k) poolbf[pq * Kn + k] = acck[k];
    }
    __syncthreads();
    for (int i = t; i < Qn * Kn; i += NTHR) pbase[i] = poolbf[i];   // coalesced

    #undef ISSUE
    #undef COMMIT
    #undef MFMA_PASS
}

__global__ __launch_bounds__(704)
void knrm_reduce(const int* __restrict__ qlen_arr, const float* __restrict__ partial,
                 const float* __restrict__ dense_w, const float* __restrict__ dense_b,
                 float* __restrict__ out)
{
    __shared__ float sq[Qn * Kn];
    __shared__ float lk[Kn];
    const int b = blockIdx.x;
    const int t = threadIdx.x;
    const int qlen = qlen_arr[b];
    if (t < Qn * Kn) {
        const int q = t / Kn, k = t - q * Kn;
        float s = 0.f;
        #pragma unroll
        for (int c = 0; c < NCHUNK; ++c)
            s += partial[(((size_t)b * NCHUNK + c) * Qn + q) * Kn + k];
        sq[t] = (q < qlen) ? 0.01f * logf(fmaxf(s, 1e-10f)) : 0.f;
    }
    __syncthreads();
    if (t < Kn) {
        float l = 0.f;
        #pragma unroll
        for (int q = 0; q < Qn; ++q) l += sq[q * Kn + t];
        out[Bn + (size_t)b * Kn + t] = l;   // log_pooling_sum (B,K)
        lk[t] = l;
    }
    __syncthreads();
    if (t == 0) {
        float sc = dense_b[0];
        #pragma unroll
        for (int k = 0; k < Kn; ++k) sc += lk[k] * dense_w[k];
        out[b] = sc;                        // score (B,)
    }
}

extern "C" void kernel_launch(void* const* d_in, const int* in_sizes, int n_in,
                              void* d_out, int out_size, void* d_ws, size_t ws_size,
                              hipStream_t stream)
{
    const int*   qidx  = (const int*)d_in[0];
    const int*   didx  = (const int*)d_in[1];
    const int*   qlen  = (const int*)d_in[2];
    const int*   dlen  = (const int*)d_in[3];
    const float* table = (const float*)d_in[4];
    const float* dw    = (const float*)d_in[5];
    const float* db    = (const float*)d_in[6];
    float* out = (float*)d_out;
    float* partial = (float*)d_ws;   // B*NCHUNK*Qn*Kn floats = 2.75 MB, fully overwritten

    knrm_main<<<dim3(Bn * NCHUNK), dim3(NTHR), 0, stream>>>(qidx, didx, dlen, table, partial);
    knrm_reduce<<<dim3(Bn), dim3(704), 0, stream>>>(qlen, partial, dw, db, out);
}

// Round 4
// 34.494 us; speedup vs baseline: 2.7265x; 1.0528x over previous
//
#include <hip/hip_runtime.h>

#define Bn 128
#define Qn 32
#define Dn 512
#define En 300
#define Kn 21
#define DC 64            // docs per block
#define NCHUNK 8         // 512/DC
#define NROWS 96         // 32 q + 64 d rows
#define LDE 40           // bf16 row stride within one k-tile (80 B)
#define TILE_SH (NROWS * LDE + 8)   // 3848 shorts per k-tile (+16B skew)
#define NKT 10           // k-tiles of 32 (covers 320 >= 300, zero-padded)
#define SIMLD 68         // sim row stride (floats)
#define NTHR 512
#define NF4 15           // float4 gathers per thread (512*15 == 96*80 exactly)

typedef __attribute__((ext_vector_type(8))) short bf16x8;
typedef __attribute__((ext_vector_type(4))) float f32x4;

// LDS: emb short[NKT][TILE_SH] = 76960 B ; idxb int[96] after it.
// Aliased into emb after last MFMA (emb dead):
//   simbuf float[32][SIMLD] @ 0      (8704 B)
//   nrm    float[96]        @ 8704   (384 B)
//   poolbf float[512*21]    @ 9088   (43008 B, ends 52096 < 76960)
#define EMB_BYTES (NKT * TILE_SH * 2)
#define SMEM_BYTES (EMB_BYTES + NROWS * 4)   // 77344 B -> 2 blocks/CU

__global__ __launch_bounds__(NTHR, 4)
void knrm_main(const int* __restrict__ qidx, const int* __restrict__ didx,
               const int* __restrict__ dlen_arr, const float* __restrict__ table,
               float* __restrict__ partial)
{
    const int t = threadIdx.x;
    const int b = blockIdx.x >> 3;
    const int chunk = blockIdx.x & 7;
    const int dlen = dlen_arr[b];
    float* pbase = partial + ((size_t)(b * NCHUNK + chunk) * Qn) * Kn;

    const int nvalid = dlen - chunk * DC;
    if (nvalid <= 0) {                 // whole chunk masked: zero partials (ws poisoned)
        for (int i = t; i < Qn * Kn; i += NTHR) pbase[i] = 0.f;
        return;
    }

    __shared__ __align__(16) char smem[SMEM_BYTES];
    short* emb    = (short*)smem;
    float* simbuf = (float*)smem;
    float* nrm    = (float*)(smem + 8704);
    float* poolbf = (float*)(smem + 9088);
    int*   idxb   = (int*)(smem + EMB_BYTES);

    // ---- stage token ids once (-1 sentinel for masked docs)
    if (t < NROWS) {
        int tok = -1;
        if (t < Qn) tok = qidx[b * Qn + t];
        else { const int dg = chunk * DC + (t - Qn); if (dg < dlen) tok = didx[b * Dn + dg]; }
        idxb[t] = tok;
    }
    __syncthreads();

    const int lane = t & 63;
    const int w = t >> 6;            // wave 0..7
    const int qt = w & 1;            // q-tile
    const int dt = w >> 1;           // d-tile
    const int frow = lane & 15;
    const int koct = lane >> 4;

    // ---- issue all 15 independent gathers (slot order: [tile][row][sub] so a
    //      wave's LDS writes land inside one k-tile -> <=2-way banks)
    float4 ld[NF4];
    #pragma unroll
    for (int i = 0; i < NF4; ++i) {
        const int u = t + i * NTHR;          // 0..7679
        const int tl = u / 768;              // k-tile
        const int rem = u - tl * 768;
        const int r = rem >> 3;
        const int sub = rem & 7;
        const int k = tl * 32 + sub * 4;
        const int tok = idxb[r];
        float4 v = {0.f, 0.f, 0.f, 0.f};
        if (k < En && tok >= 0) v = *(const float4*)(table + (size_t)tok * En + k);
        ld[i] = v;
    }
    // ---- commit: round-half-up bf16 pack via v_perm, 8B LDS writes
    #pragma unroll
    for (int i = 0; i < NF4; ++i) {
        const int u = t + i * NTHR;
        const int tl = u / 768;
        const int rem = u - tl * 768;
        const int r = rem >> 3;
        const int sub = rem & 7;
        const unsigned ax = __float_as_uint(ld[i].x) + 0x8000u;
        const unsigned ay = __float_as_uint(ld[i].y) + 0x8000u;
        const unsigned az = __float_as_uint(ld[i].z) + 0x8000u;
        const unsigned aw = __float_as_uint(ld[i].w) + 0x8000u;
        uint2 p;
        p.x = __builtin_amdgcn_perm(ay, ax, 0x07060302u);
        p.y = __builtin_amdgcn_perm(aw, az, 0x07060302u);
        *(uint2*)&emb[tl * TILE_SH + r * LDE + sub * 4] = p;
    }
    __syncthreads();

    // ---- MFMA: sim tile per wave + d-gram (even waves) + q-gram (waves 0,1)
    f32x4 accS = {0.f,0.f,0.f,0.f};
    f32x4 accG = {0.f,0.f,0.f,0.f};
    f32x4 accQ = {0.f,0.f,0.f,0.f};
    #pragma unroll
    for (int kt = 0; kt < NKT; ++kt) {
        const short* base = &emb[kt * TILE_SH];
        bf16x8 a  = *(const bf16x8*)&base[(qt * 16 + frow) * LDE + koct * 8];
        bf16x8 bb = *(const bf16x8*)&base[(Qn + dt * 16 + frow) * LDE + koct * 8];
        accS = __builtin_amdgcn_mfma_f32_16x16x32_bf16(a, bb, accS, 0, 0, 0);
        if ((w & 1) == 0) accG = __builtin_amdgcn_mfma_f32_16x16x32_bf16(bb, bb, accG, 0, 0, 0);
        if (w < 2)        accQ = __builtin_amdgcn_mfma_f32_16x16x32_bf16(a, a, accQ, 0, 0, 0);
    }
    __syncthreads();    // emb dead -> aliases live

    // ---- gram diagonals -> inverse norms (C layout: col=lane&15, row=koct*4+reg)
    if (koct == (frow >> 2)) {
        const int rm = frow & 3;
        if ((w & 1) == 0) {
            const float g = (rm == 0) ? accG[0] : (rm == 1) ? accG[1] : (rm == 2) ? accG[2] : accG[3];
            nrm[Qn + dt * 16 + frow] = 1.0f / fmaxf(sqrtf(g), 1e-12f);
        }
        if (w < 2) {
            const float g = (rm == 0) ? accQ[0] : (rm == 1) ? accQ[1] : (rm == 2) ? accQ[2] : accQ[3];
            nrm[qt * 16 + frow] = 1.0f / fmaxf(sqrtf(g), 1e-12f);
        }
    }
    __syncthreads();

    // ---- scale sims, write tile
    const float id = nrm[Qn + dt * 16 + frow];
    #pragma unroll
    for (int reg = 0; reg < 4; ++reg) {
        const int q = qt * 16 + koct * 4 + reg;
        simbuf[q * SIMLD + dt * 16 + frow] = accS[reg] * nrm[q] * id;
    }
    __syncthreads();

    // ---- Gaussian pooling: 16 lanes per q, 4 docs each; sentinel for masked
    const int pq = t >> 4;
    const int pdl = t & 15;
    float sv[4];
    #pragma unroll
    for (int j = 0; j < 4; ++j) {
        const int d = pdl + 16 * j;
        sv[j] = (chunk * DC + d < dlen) ? simbuf[pq * SIMLD + d] : 1.0e3f;  // all kernels -> 0
    }
    float acck[Kn];
    #pragma unroll
    for (int k = 0; k < Kn; ++k) acck[k] = 0.f;
    #pragma unroll
    for (int j = 0; j < 4; ++j) {
        const float s = sv[j];
        #pragma unroll
        for (int k = 0; k < Kn; ++k) {
            const float mu = (k == 0) ? 1.0f : (0.95f - 0.1f * (float)(k - 1));
            const float cf = (k == 0) ? -500000.0f : -50.0f;  // -1/(2*sigma^2)
            const float df = s - mu;
            acck[k] += __expf(cf * df * df);
        }
    }
    // per-thread accs -> LDS (stride 21 floats: odd -> conflict-free)
    #pragma unroll
    for (int k = 0; k < Kn; ++k) poolbf[t * Kn + k] = acck[k];
    __syncthreads();

    // ---- phase 2: sum the 16 lanes of each q, write partial directly
    for (int i = t; i < Qn * Kn; i += NTHR) {
        const int q = i / Kn;
        const int k = i - q * Kn;
        float s = 0.f;
        #pragma unroll
        for (int p = 0; p < 16; ++p) s += poolbf[(q * 16 + p) * Kn + k];
        pbase[i] = s;
    }
}

__global__ __launch_bounds__(704)
void knrm_reduce(const int* __restrict__ qlen_arr, const float* __restrict__ partial,
                 const float* __restrict__ dense_w, const float* __restrict__ dense_b,
                 float* __restrict__ out)
{
    __shared__ float sq[Qn * Kn];
    __shared__ float lk[Kn];
    const int b = blockIdx.x;
    const int t = threadIdx.x;
    const int qlen = qlen_arr[b];
    if (t < Qn * Kn) {
        const int q = t / Kn, k = t - q * Kn;
        float s = 0.f;
        #pragma unroll
        for (int c = 0; c < NCHUNK; ++c)
            s += partial[(((size_t)b * NCHUNK + c) * Qn + q) * Kn + k];
        sq[t] = (q < qlen) ? 0.01f * logf(fmaxf(s, 1e-10f)) : 0.f;
    }
    __syncthreads();
    if (t < Kn) {
        float l = 0.f;
        #pragma unroll
        for (int q = 0; q < Qn; ++q) l += sq[q * Kn + t];
        out[Bn + (size_t)b * Kn + t] = l;   // log_pooling_sum (B,K)
        lk[t] = l;
    }
    __syncthreads();
    if (t == 0) {
        float sc = dense_b[0];
        #pragma unroll
        for (int k = 0; k < Kn; ++k) sc += lk[k] * dense_w[k];
        out[b] = sc;                        // score (B,)
    }
}

extern "C" void kernel_launch(void* const* d_in, const int* in_sizes, int n_in,
                              void* d_out, int out_size, void* d_ws, size_t ws_size,
                              hipStream_t stream)
{
    const int*   qidx  = (const int*)d_in[0];
    const int*   didx  = (const int*)d_in[1];
    const int*   qlen  = (const int*)d_in[2];
    const int*   dlen  = (const int*)d_in[3];
    const float* table = (const float*)d_in[4];
    const float* dw    = (const float*)d_in[5];
    const float* db    = (const float*)d_in[6];
    float* out = (float*)d_out;
    float* partial = (float*)d_ws;   // B*NCHUNK*Qn*Kn floats = 2.75 MB, fully overwritten

    knrm_main<<<dim3(Bn * NCHUNK), dim3(NTHR), 0, stream>>>(qidx, didx, dlen, table, partial);
    knrm_reduce<<<dim3(Bn), dim3(704), 0, stream>>>(qlen, partial, dw, db, out);
}

// Round 5
// 29.586 us; speedup vs baseline: 3.1788x; 1.1659x over previous
//
#include <hip/hip_runtime.h>

#define Bn 128
#define Qn 32
#define Dn 512
#define En 300
#define Kn 21
#define CH 32                  // docs per chunk
#define JBLK 4                 // blocks per batch
#define MAXIT 4                // max chunk iterations per block (JBLK*MAXIT*CH = 512)
#define LDE 40                 // shorts per row within one k-tile (80 B)
#define NKT 10                 // k-tiles of 32 (covers 320 >= 300, zero-padded)
#define TILE_SH (CH * LDE)     // 1280 shorts per k-tile
#define BUF_SH (NKT * TILE_SH) // 12800 shorts = 25600 B per 32-row buffer
#define NTHR 256

typedef __attribute__((ext_vector_type(8))) short bf16x8;
typedef __attribute__((ext_vector_type(4))) float f32x4;

// LDS map (bytes):
//   qbuf  [0,      25600)   short[NKT][CH][LDE]
//   dbuf0 [25600,  51200)
//   dbuf1 [51200,  76800)
//   idx   [76800,  77440)   int[MAXIT*CH + Qn]
//   poolbf aliases qbuf (dead after a-frag hoist) in the epilogue
#define SMEM_BYTES 77440       // -> 2 blocks/CU

__device__ __forceinline__ float dot4(float4 a, float4 b) {
    return a.x * b.x + a.y * b.y + a.z * b.z + a.w * b.w;
}

__global__ __launch_bounds__(NTHR, 2)
void knrm_main(const int* __restrict__ qidx, const int* __restrict__ didx,
               const int* __restrict__ dlen_arr, const float* __restrict__ table,
               float* __restrict__ partial)
{
    const int t = threadIdx.x;
    const int b = blockIdx.x >> 2;
    const int j = blockIdx.x & 3;
    const int dlen = dlen_arr[b];
    float* pbase = partial + ((size_t)(b * JBLK + j) * Qn) * Kn;

    // chunks for this block: c = j + 4*i, i = 0..nc-1 (monotone in i)
    int nc = 0;
    #pragma unroll
    for (int i = 0; i < MAXIT; ++i) if ((j + JBLK * i) * CH < dlen) nc = i + 1;

    if (nc == 0) {               // nothing to do: zero partial (ws is poisoned)
        for (int i = t; i < Qn * Kn; i += NTHR) pbase[i] = 0.f;
        return;
    }

    __shared__ __align__(16) char smem[SMEM_BYTES];
    short* qbuf   = (short*)smem;
    short* dbufA  = (short*)(smem + 25600);
    short* dbufB  = (short*)(smem + 51200);
    int*   idxd   = (int*)(smem + 76800);     // [MAXIT][CH]
    int*   idxq   = idxd + MAXIT * CH;        // [Qn]
    float* poolbf = (float*)smem;             // alias (epilogue only)

    // ---- stage tokens (-1 sentinel -> zero rows)
    if (t < MAXIT * CH) {
        const int i = t >> 5, r = t & 31;
        const int doc = (j + JBLK * i) * CH + r;
        idxd[t] = (doc < dlen) ? didx[b * Dn + doc] : -1;
    } else if (t < MAXIT * CH + Qn) {
        idxq[t - MAXIT * CH] = qidx[b * Qn + (t - MAXIT * CH)];
    }
    __syncthreads();

    const int row = t >> 3;      // one LDS row per 8-lane octet (32 rows / 256 thr)
    const int il  = t & 7;

    float4 ld[NKT];
    // issue: 10 independent gathers for this octet's row
    auto issue = [&](int tok) {
        #pragma unroll
        for (int j2 = 0; j2 < NKT; ++j2) {
            const int k = j2 * 32 + il * 4;
            float4 v = {0.f, 0.f, 0.f, 0.f};
            if (k < En && tok >= 0) v = *(const float4*)(table + (size_t)tok * En + k);
            ld[j2] = v;
        }
    };
    // commit: octet row-norm (3-level shfl), scale, bf16 pack, 8B LDS writes
    auto commit = [&](short* dst) {
        float ss = 0.f;
        #pragma unroll
        for (int j2 = 0; j2 < NKT; ++j2) ss += dot4(ld[j2], ld[j2]);
        ss += __shfl_xor(ss, 1);
        ss += __shfl_xor(ss, 2);
        ss += __shfl_xor(ss, 4);
        const float inv = 1.0f / fmaxf(sqrtf(ss), 1e-12f);
        #pragma unroll
        for (int j2 = 0; j2 < NKT; ++j2) {
            const unsigned ax = __float_as_uint(ld[j2].x * inv) + 0x8000u;
            const unsigned ay = __float_as_uint(ld[j2].y * inv) + 0x8000u;
            const unsigned az = __float_as_uint(ld[j2].z * inv) + 0x8000u;
            const unsigned aw = __float_as_uint(ld[j2].w * inv) + 0x8000u;
            uint2 p;
            p.x = __builtin_amdgcn_perm(ay, ax, 0x07060302u);
            p.y = __builtin_amdgcn_perm(aw, az, 0x07060302u);
            *(uint2*)&dst[j2 * TILE_SH + row * LDE + il * 4] = p;
        }
    };

    const int lane = t & 63;
    const int w = t >> 6;        // wave 0..3 -> tile (qt, dt)
    const int qt = w & 1;
    const int dt = w >> 1;
    const int frow = lane & 15;
    const int koct = lane >> 4;

    // ---- prologue: q rows (normalized), then chunk 0
    issue(idxq[row]);
    commit(qbuf);
    issue(idxd[row]);            // chunk 0 docs, in flight over the barrier
    __syncthreads();

    bf16x8 af[NKT];              // hoist loop-invariant q fragments
    #pragma unroll
    for (int kt = 0; kt < NKT; ++kt)
        af[kt] = *(const bf16x8*)&qbuf[kt * TILE_SH + (qt * 16 + frow) * LDE + koct * 8];

    commit(dbufA);
    __syncthreads();

    float acc[4][Kn];
    #pragma unroll
    for (int r = 0; r < 4; ++r)
        #pragma unroll
        for (int k = 0; k < Kn; ++k) acc[r][k] = 0.f;

    int p = 0;
    for (int it = 0; it < nc; ++it) {
        const bool more = (it + 1 < nc);
        if (more) issue(idxd[(it + 1) * CH + row]);   // latency hides under MFMA+pool

        const short* db = p ? dbufB : dbufA;
        f32x4 accS = {0.f, 0.f, 0.f, 0.f};
        #pragma unroll
        for (int kt = 0; kt < NKT; ++kt) {
            bf16x8 bf = *(const bf16x8*)&db[kt * TILE_SH + (dt * 16 + frow) * LDE + koct * 8];
            accS = __builtin_amdgcn_mfma_f32_16x16x32_bf16(af[kt], bf, accS, 0, 0, 0);
        }

        // pool straight from the fragment: this thread's doc col = dt*16+frow
        const int doc = (j + JBLK * it) * CH + dt * 16 + frow;
        if (doc < dlen) {
            #pragma unroll
            for (int r = 0; r < 4; ++r) {
                const float s = accS[r];     // already normalized (both operands unit rows)
                #pragma unroll
                for (int k = 0; k < Kn; ++k) {
                    const float mu = (k == 0) ? 1.0f : (0.95f - 0.1f * (float)(k - 1));
                    const float cf = (k == 0) ? -500000.0f : -50.0f;  // -1/(2*sigma^2)
                    const float df = s - mu;
                    acc[r][k] += __expf(cf * df * df);
                }
            }
        }

        if (more) commit(p ? dbufA : dbufB);
        __syncthreads();
        p ^= 1;
    }

    // ---- epilogue: 4 rounds (one per reg), LDS reduce over 2 dt x 16 cols
    #pragma unroll
    for (int r = 0; r < 4; ++r) {
        #pragma unroll
        for (int k = 0; k < Kn; ++k) poolbf[t * Kn + k] = acc[r][k];
        __syncthreads();
        for (int i = t; i < 8 * Kn; i += NTHR) {     // 168 outputs this round
            const int qq = i / Kn;                   // 0..7
            const int k  = i - qq * Kn;
            const int qt2 = qq >> 2, ko2 = qq & 3;
            float s = 0.f;
            #pragma unroll
            for (int dt2 = 0; dt2 < 2; ++dt2)
                #pragma unroll
                for (int col = 0; col < 16; ++col)
                    s += poolbf[((qt2 + 2 * dt2) * 64 + ko2 * 16 + col) * Kn + k];
            pbase[(qt2 * 16 + ko2 * 4 + r) * Kn + k] = s;
        }
        __syncthreads();
    }
}

__global__ __launch_bounds__(704)
void knrm_reduce(const int* __restrict__ qlen_arr, const float* __restrict__ partial,
                 const float* __restrict__ dense_w, const float* __restrict__ dense_b,
                 float* __restrict__ out)
{
    __shared__ float sq[Qn * Kn];
    __shared__ float lk[Kn];
    const int b = blockIdx.x;
    const int t = threadIdx.x;
    const int qlen = qlen_arr[b];
    if (t < Qn * Kn) {
        const int q = t / Kn, k = t - q * Kn;
        float s = 0.f;
        #pragma unroll
        for (int c = 0; c < JBLK; ++c)
            s += partial[(((size_t)b * JBLK + c) * Qn + q) * Kn + k];
        sq[t] = (q < qlen) ? 0.01f * logf(fmaxf(s, 1e-10f)) : 0.f;
    }
    __syncthreads();
    if (t < Kn) {
        float l = 0.f;
        #pragma unroll
        for (int q = 0; q < Qn; ++q) l += sq[q * Kn + t];
        out[Bn + (size_t)b * Kn + t] = l;   // log_pooling_sum (B,K)
        lk[t] = l;
    }
    __syncthreads();
    if (t == 0) {
        float sc = dense_b[0];
        #pragma unroll
        for (int k = 0; k < Kn; ++k) sc += lk[k] * dense_w[k];
        out[b] = sc;                        // score (B,)
    }
}

extern "C" void kernel_launch(void* const* d_in, const int* in_sizes, int n_in,
                              void* d_out, int out_size, void* d_ws, size_t ws_size,
                              hipStream_t stream)
{
    const int*   qidx  = (const int*)d_in[0];
    const int*   didx  = (const int*)d_in[1];
    const int*   qlen  = (const int*)d_in[2];
    const int*   dlen  = (const int*)d_in[3];
    const float* table = (const float*)d_in[4];
    const float* dw    = (const float*)d_in[5];
    const float* db    = (const float*)d_in[6];
    float* out = (float*)d_out;
    float* partial = (float*)d_ws;   // B*JBLK*Qn*Kn floats = 1.38 MB, fully overwritten

    knrm_main<<<dim3(Bn * JBLK), dim3(NTHR), 0, stream>>>(qidx, didx, dlen, table, partial);
    knrm_reduce<<<dim3(Bn), dim3(704), 0, stream>>>(qlen, partial, dw, db, out);
}